// Round 2
// baseline (996.469 us; speedup 1.0000x reference)
//
#include <hip/hip_runtime.h>
#include <math.h>

#define D_MODEL 512
#define HEAD_DIM 64
#define NUM_HEADS 8
#define SEQ 2048
#define BATCH 4
#define ROWS (BATCH * SEQ)  // 8192

// ---------------------------------------------------------------------------
// Projection GEMM: y = x @ W^T + b (torch Linear). M=8192, N=512, K=512.
// BM=BN=128, BK=16, 256 threads, 8x8 register tile (split as 4+4 rows/cols:
// rows ty*4+i and 64+ty*4+i, cols tx*4+j and 64+tx*4+j) so LDS B-reads are
// 2-way aliased (free) instead of 4-way. LDS k-major, pitch 132 (132%32=4):
// A-reads broadcast conflict-free, staging writes 2-way (free).
// gridDim.z selects q/k/v.
// ---------------------------------------------------------------------------
__global__ __launch_bounds__(256) void mha_proj_kernel(
    const float* __restrict__ q, const float* __restrict__ k,
    const float* __restrict__ v, const float* __restrict__ Wq,
    const float* __restrict__ bq, const float* __restrict__ Wk,
    const float* __restrict__ bk, const float* __restrict__ Wv,
    const float* __restrict__ bv, float* __restrict__ qp,
    float* __restrict__ kp, float* __restrict__ vp) {
  const float* x;
  const float* W;
  const float* bias;
  float* y;
  if (blockIdx.z == 0) {
    x = q; W = Wq; bias = bq; y = qp;
  } else if (blockIdx.z == 1) {
    x = k; W = Wk; bias = bk; y = kp;
  } else {
    x = v; W = Wv; bias = bv; y = vp;
  }

  __shared__ float Xs[16][132];
  __shared__ float Ws[16][132];

  const int tid = threadIdx.x;
  const int row0 = blockIdx.x * 128;
  const int col0 = blockIdx.y * 128;
  const int tx = tid & 15;       // 0..15
  const int ty = tid >> 4;       // 0..15
  const int lr = tid >> 1;       // staging row 0..127
  const int lk = (tid & 1) * 8;  // staging k offset 0 or 8

  float acc[8][8] = {};

  for (int k0 = 0; k0 < D_MODEL; k0 += 16) {
    // issue global loads before the barrier (overlap previous compute)
    const float4 xa = *reinterpret_cast<const float4*>(
        &x[(size_t)(row0 + lr) * D_MODEL + k0 + lk]);
    const float4 xb = *reinterpret_cast<const float4*>(
        &x[(size_t)(row0 + lr) * D_MODEL + k0 + lk + 4]);
    const float4 wa = *reinterpret_cast<const float4*>(
        &W[(size_t)(col0 + lr) * D_MODEL + k0 + lk]);
    const float4 wb = *reinterpret_cast<const float4*>(
        &W[(size_t)(col0 + lr) * D_MODEL + k0 + lk + 4]);
    __syncthreads();
    Xs[lk + 0][lr] = xa.x; Xs[lk + 1][lr] = xa.y;
    Xs[lk + 2][lr] = xa.z; Xs[lk + 3][lr] = xa.w;
    Xs[lk + 4][lr] = xb.x; Xs[lk + 5][lr] = xb.y;
    Xs[lk + 6][lr] = xb.z; Xs[lk + 7][lr] = xb.w;
    Ws[lk + 0][lr] = wa.x; Ws[lk + 1][lr] = wa.y;
    Ws[lk + 2][lr] = wa.z; Ws[lk + 3][lr] = wa.w;
    Ws[lk + 4][lr] = wb.x; Ws[lk + 5][lr] = wb.y;
    Ws[lk + 6][lr] = wb.z; Ws[lk + 7][lr] = wb.w;
    __syncthreads();
#pragma unroll
    for (int kk = 0; kk < 16; ++kk) {
      float a[8], bb[8];
      *reinterpret_cast<float4*>(&a[0]) =
          *reinterpret_cast<const float4*>(&Xs[kk][ty * 4]);
      *reinterpret_cast<float4*>(&a[4]) =
          *reinterpret_cast<const float4*>(&Xs[kk][64 + ty * 4]);
      *reinterpret_cast<float4*>(&bb[0]) =
          *reinterpret_cast<const float4*>(&Ws[kk][tx * 4]);
      *reinterpret_cast<float4*>(&bb[4]) =
          *reinterpret_cast<const float4*>(&Ws[kk][64 + tx * 4]);
#pragma unroll
      for (int i = 0; i < 8; ++i)
#pragma unroll
        for (int j = 0; j < 8; ++j) acc[i][j] += a[i] * bb[j];
    }
  }

  float bias_lo[4], bias_hi[4];
  *reinterpret_cast<float4*>(&bias_lo[0]) =
      *reinterpret_cast<const float4*>(&bias[col0 + tx * 4]);
  *reinterpret_cast<float4*>(&bias_hi[0]) =
      *reinterpret_cast<const float4*>(&bias[col0 + 64 + tx * 4]);
#pragma unroll
  for (int i = 0; i < 8; ++i) {
    const int row = row0 + ((i < 4) ? (ty * 4 + i) : (64 + ty * 4 + i - 4));
    float4 lo, hi;
    lo.x = acc[i][0] + bias_lo[0]; lo.y = acc[i][1] + bias_lo[1];
    lo.z = acc[i][2] + bias_lo[2]; lo.w = acc[i][3] + bias_lo[3];
    hi.x = acc[i][4] + bias_hi[0]; hi.y = acc[i][5] + bias_hi[1];
    hi.z = acc[i][6] + bias_hi[2]; hi.w = acc[i][7] + bias_hi[3];
    *reinterpret_cast<float4*>(&y[(size_t)row * D_MODEL + col0 + tx * 4]) = lo;
    *reinterpret_cast<float4*>(
        &y[(size_t)row * D_MODEL + col0 + 64 + tx * 4]) = hi;
  }
}

// ---------------------------------------------------------------------------
// Flash-style attention, fp32. One block = one (b, h, 64-row q-tile).
// 256 threads, 8 lanes per group; group g owns q-rows g and g+32.
// Two rows per thread doubles FMAs per LDS byte (the round-0 design was
// LDS-read-bound ~2.9x over VALU; this brings reads/FMA 0.28 -> 0.156).
// Online softmax per row (m,l); ctx 2x8 dims in registers.
// Pitch-68 LDS: Q/K reads cover all 32 banks (conflict-free), V reads 2-way
// (free), staging writes 2-way (free).
// ---------------------------------------------------------------------------
__global__ __launch_bounds__(256) void mha_attn_kernel(
    const float* __restrict__ qp, const float* __restrict__ kp,
    const float* __restrict__ vp, float* __restrict__ out) {
  __shared__ float Qs[64][68];
  __shared__ float Ks[32][68];
  __shared__ float Vs[32][68];

  const int tid = threadIdx.x;
  const int bid = blockIdx.x;
  const int qt = bid & 31;        // q-tile 0..31 (64 rows each)
  const int h = (bid >> 5) & 7;   // head
  const int b = bid >> 8;         // batch

  const size_t head_off = (size_t)h * HEAD_DIM;
  const size_t qbase = ((size_t)b * SEQ + (size_t)qt * 64) * D_MODEL + head_off;
  const size_t kvbase0 = (size_t)b * SEQ * D_MODEL + head_off;

  const int sr = tid >> 4;        // staging row 0..15
  const int sc = (tid & 15) * 4;  // staging col 0..60

  // stage the 64-row Q tile once
#pragma unroll
  for (int i = 0; i < 4; ++i) {
    const float4 qv = *reinterpret_cast<const float4*>(
        &qp[qbase + (size_t)(sr + 16 * i) * D_MODEL + sc]);
    *reinterpret_cast<float4*>(&Qs[sr + 16 * i][sc]) = qv;
  }

  const int g = tid >> 3;   // group 0..31 -> q-rows g and g+32
  const int gl = tid & 7;   // lane in group
  const int d0 = gl * 8;    // this thread's 8 output dims

  float ctx0[8] = {0.f, 0.f, 0.f, 0.f, 0.f, 0.f, 0.f, 0.f};
  float ctx1[8] = {0.f, 0.f, 0.f, 0.f, 0.f, 0.f, 0.f, 0.f};
  float m0 = -3.0e38f, m1 = -3.0e38f;
  float l0 = 0.f, l1 = 0.f;

  for (int kt = 0; kt < SEQ / 32; ++kt) {
    const size_t kvb = kvbase0 + (size_t)kt * 32 * D_MODEL;
    // issue global loads before the barrier: latency overlaps prior compute
    const float4 ka0 = *reinterpret_cast<const float4*>(
        &kp[kvb + (size_t)sr * D_MODEL + sc]);
    const float4 ka1 = *reinterpret_cast<const float4*>(
        &kp[kvb + (size_t)(sr + 16) * D_MODEL + sc]);
    const float4 va0 = *reinterpret_cast<const float4*>(
        &vp[kvb + (size_t)sr * D_MODEL + sc]);
    const float4 va1 = *reinterpret_cast<const float4*>(
        &vp[kvb + (size_t)(sr + 16) * D_MODEL + sc]);
    __syncthreads();  // previous tile's LDS reads done (covers Q stage too)
    *reinterpret_cast<float4*>(&Ks[sr][sc]) = ka0;
    *reinterpret_cast<float4*>(&Ks[sr + 16][sc]) = ka1;
    *reinterpret_cast<float4*>(&Vs[sr][sc]) = va0;
    *reinterpret_cast<float4*>(&Vs[sr + 16][sc]) = va1;
    __syncthreads();

    // ---- scores for 2 q-rows x 4 k-cols (ki = gl, gl+8, gl+16, gl+24) ----
    float s0[4] = {0.f, 0.f, 0.f, 0.f};
    float s1[4] = {0.f, 0.f, 0.f, 0.f};
#pragma unroll
    for (int d4 = 0; d4 < 16; ++d4) {
      const float4 qa = *reinterpret_cast<const float4*>(&Qs[g][d4 * 4]);
      const float4 qb = *reinterpret_cast<const float4*>(&Qs[g + 32][d4 * 4]);
      const float4 k_a = *reinterpret_cast<const float4*>(&Ks[gl][d4 * 4]);
      const float4 k_b = *reinterpret_cast<const float4*>(&Ks[gl + 8][d4 * 4]);
      const float4 k_c = *reinterpret_cast<const float4*>(&Ks[gl + 16][d4 * 4]);
      const float4 k_d = *reinterpret_cast<const float4*>(&Ks[gl + 24][d4 * 4]);
      s0[0] += qa.x * k_a.x + qa.y * k_a.y + qa.z * k_a.z + qa.w * k_a.w;
      s0[1] += qa.x * k_b.x + qa.y * k_b.y + qa.z * k_b.z + qa.w * k_b.w;
      s0[2] += qa.x * k_c.x + qa.y * k_c.y + qa.z * k_c.z + qa.w * k_c.w;
      s0[3] += qa.x * k_d.x + qa.y * k_d.y + qa.z * k_d.z + qa.w * k_d.w;
      s1[0] += qb.x * k_a.x + qb.y * k_a.y + qb.z * k_a.z + qb.w * k_a.w;
      s1[1] += qb.x * k_b.x + qb.y * k_b.y + qb.z * k_b.z + qb.w * k_b.w;
      s1[2] += qb.x * k_c.x + qb.y * k_c.y + qb.z * k_c.z + qb.w * k_c.w;
      s1[3] += qb.x * k_d.x + qb.y * k_d.y + qb.z * k_d.z + qb.w * k_d.w;
    }
#pragma unroll
    for (int j = 0; j < 4; ++j) {
      s0[j] *= 0.125f;  // 1/sqrt(64)
      s1[j] *= 0.125f;
    }

    // ---- online softmax, row 0 ----
    float smax0 = fmaxf(fmaxf(s0[0], s0[1]), fmaxf(s0[2], s0[3]));
    smax0 = fmaxf(smax0, __shfl_xor(smax0, 1, 8));
    smax0 = fmaxf(smax0, __shfl_xor(smax0, 2, 8));
    smax0 = fmaxf(smax0, __shfl_xor(smax0, 4, 8));
    const float mnew0 = fmaxf(m0, smax0);
    const float alpha0 = __expf(m0 - mnew0);
    float p0[4];
    float ps0 = 0.f;
#pragma unroll
    for (int j = 0; j < 4; ++j) {
      p0[j] = __expf(s0[j] - mnew0);
      ps0 += p0[j];
    }
    ps0 += __shfl_xor(ps0, 1, 8);
    ps0 += __shfl_xor(ps0, 2, 8);
    ps0 += __shfl_xor(ps0, 4, 8);
    l0 = l0 * alpha0 + ps0;
    m0 = mnew0;
#pragma unroll
    for (int i = 0; i < 8; ++i) ctx0[i] *= alpha0;

    // ---- online softmax, row 1 ----
    float smax1 = fmaxf(fmaxf(s1[0], s1[1]), fmaxf(s1[2], s1[3]));
    smax1 = fmaxf(smax1, __shfl_xor(smax1, 1, 8));
    smax1 = fmaxf(smax1, __shfl_xor(smax1, 2, 8));
    smax1 = fmaxf(smax1, __shfl_xor(smax1, 4, 8));
    const float mnew1 = fmaxf(m1, smax1);
    const float alpha1 = __expf(m1 - mnew1);
    float p1[4];
    float ps1 = 0.f;
#pragma unroll
    for (int j = 0; j < 4; ++j) {
      p1[j] = __expf(s1[j] - mnew1);
      ps1 += p1[j];
    }
    ps1 += __shfl_xor(ps1, 1, 8);
    ps1 += __shfl_xor(ps1, 2, 8);
    ps1 += __shfl_xor(ps1, 4, 8);
    l1 = l1 * alpha1 + ps1;
    m1 = mnew1;
#pragma unroll
    for (int i = 0; i < 8; ++i) ctx1[i] *= alpha1;

    // ---- PV: broadcast p within the 8-lane group, accumulate 2x8 dims ----
#pragma unroll
    for (int ki = 0; ki < 32; ++ki) {
      const float pb0 = __shfl(p0[ki >> 3], ki & 7, 8);
      const float pb1 = __shfl(p1[ki >> 3], ki & 7, 8);
      const float4 va = *reinterpret_cast<const float4*>(&Vs[ki][d0]);
      const float4 vb = *reinterpret_cast<const float4*>(&Vs[ki][d0 + 4]);
      ctx0[0] += pb0 * va.x; ctx0[1] += pb0 * va.y;
      ctx0[2] += pb0 * va.z; ctx0[3] += pb0 * va.w;
      ctx0[4] += pb0 * vb.x; ctx0[5] += pb0 * vb.y;
      ctx0[6] += pb0 * vb.z; ctx0[7] += pb0 * vb.w;
      ctx1[0] += pb1 * va.x; ctx1[1] += pb1 * va.y;
      ctx1[2] += pb1 * va.z; ctx1[3] += pb1 * va.w;
      ctx1[4] += pb1 * vb.x; ctx1[5] += pb1 * vb.y;
      ctx1[6] += pb1 * vb.z; ctx1[7] += pb1 * vb.w;
    }
  }

  const float inv0 = 1.0f / l0;
  const float inv1 = 1.0f / l1;
  float4 o;
  float* orow0 = &out[qbase + (size_t)g * D_MODEL + d0];
  o.x = ctx0[0] * inv0; o.y = ctx0[1] * inv0;
  o.z = ctx0[2] * inv0; o.w = ctx0[3] * inv0;
  *reinterpret_cast<float4*>(orow0) = o;
  o.x = ctx0[4] * inv0; o.y = ctx0[5] * inv0;
  o.z = ctx0[6] * inv0; o.w = ctx0[7] * inv0;
  *reinterpret_cast<float4*>(orow0 + 4) = o;
  float* orow1 = &out[qbase + (size_t)(g + 32) * D_MODEL + d0];
  o.x = ctx1[0] * inv1; o.y = ctx1[1] * inv1;
  o.z = ctx1[2] * inv1; o.w = ctx1[3] * inv1;
  *reinterpret_cast<float4*>(orow1) = o;
  o.x = ctx1[4] * inv1; o.y = ctx1[5] * inv1;
  o.z = ctx1[6] * inv1; o.w = ctx1[7] * inv1;
  *reinterpret_cast<float4*>(orow1 + 4) = o;
}

extern "C" void kernel_launch(void* const* d_in, const int* in_sizes, int n_in,
                              void* d_out, int out_size, void* d_ws,
                              size_t ws_size, hipStream_t stream) {
  const float* q = (const float*)d_in[0];
  const float* k = (const float*)d_in[1];
  const float* v = (const float*)d_in[2];
  const float* Wq_w = (const float*)d_in[3];
  const float* Wq_b = (const float*)d_in[4];
  const float* Wk_w = (const float*)d_in[5];
  const float* Wk_b = (const float*)d_in[6];
  const float* Wv_w = (const float*)d_in[7];
  const float* Wv_b = (const float*)d_in[8];
  float* out = (float*)d_out;

  float* qp = (float*)d_ws;                 // [8192, 512]
  float* kp = qp + (size_t)ROWS * D_MODEL;  // [8192, 512]
  float* vp = kp + (size_t)ROWS * D_MODEL;  // [8192, 512]

  // fused QKV projection: grid.z picks q/k/v
  dim3 pgrid(ROWS / 128, D_MODEL / 128, 3);
  mha_proj_kernel<<<pgrid, 256, 0, stream>>>(q, k, v, Wq_w, Wq_b, Wk_w, Wk_b,
                                             Wv_w, Wv_b, qp, kp, vp);

  // flash attention: one block per (b, h, 64-row q-tile)
  dim3 agrid(BATCH * NUM_HEADS * (SEQ / 64));
  mha_attn_kernel<<<agrid, 256, 0, stream>>>(qp, kp, vp, out);
}

// Round 3
// 424.079 us; speedup vs baseline: 2.3497x; 2.3497x over previous
//
#include <hip/hip_runtime.h>
#include <math.h>

#define D_MODEL 512
#define HEAD_DIM 64
#define NUM_HEADS 8
#define SEQ 2048
#define BATCH 4
#define ROWS (BATCH * SEQ)  // 8192
#define PLANE ((size_t)ROWS * D_MODEL)  // 4194304 elems

typedef short v8s __attribute__((ext_vector_type(8)));
typedef float v4f __attribute__((ext_vector_type(4)));

#define MFMA16(a, b, c) __builtin_amdgcn_mfma_f32_16x16x32_bf16(a, b, c, 0, 0, 0)

__device__ __forceinline__ unsigned short bf16_rne(float x) {
  unsigned u = __float_as_uint(x);
  u += 0x7fffu + ((u >> 16) & 1u);
  return (unsigned short)(u >> 16);
}
__device__ __forceinline__ float bf16f(unsigned short h) {
  return __uint_as_float(((unsigned)h) << 16);
}

// ---------------------------------------------------------------------------
// Projection GEMM (fp32 VALU, core validated in r1): y = x @ W^T + b.
// Epilogue now emits bf16 planes: z<2 -> hi+lo split (RNE hi, exact-residual
// lo), z==2 -> single RNE bf16 V plane (row-major, transposed by vtrans).
// ---------------------------------------------------------------------------
__global__ __launch_bounds__(256) void mha_proj_kernel(
    const float* __restrict__ q, const float* __restrict__ k,
    const float* __restrict__ v, const float* __restrict__ Wq,
    const float* __restrict__ bq, const float* __restrict__ Wk,
    const float* __restrict__ bk, const float* __restrict__ Wv,
    const float* __restrict__ bv, unsigned short* __restrict__ q_hi,
    unsigned short* __restrict__ q_lo, unsigned short* __restrict__ k_hi,
    unsigned short* __restrict__ k_lo, unsigned short* __restrict__ v_b) {
  const float* x;
  const float* W;
  const float* bias;
  if (blockIdx.z == 0) {
    x = q; W = Wq; bias = bq;
  } else if (blockIdx.z == 1) {
    x = k; W = Wk; bias = bk;
  } else {
    x = v; W = Wv; bias = bv;
  }

  __shared__ float Xs[16][132];
  __shared__ float Ws[16][132];

  const int tid = threadIdx.x;
  const int row0 = blockIdx.x * 128;
  const int col0 = blockIdx.y * 128;
  const int tx = tid & 15;
  const int ty = tid >> 4;
  const int lr = tid >> 1;
  const int lk = (tid & 1) * 8;

  float acc[8][8] = {};

  for (int k0 = 0; k0 < D_MODEL; k0 += 16) {
    const float4 xa = *reinterpret_cast<const float4*>(
        &x[(size_t)(row0 + lr) * D_MODEL + k0 + lk]);
    const float4 xb = *reinterpret_cast<const float4*>(
        &x[(size_t)(row0 + lr) * D_MODEL + k0 + lk + 4]);
    const float4 wa = *reinterpret_cast<const float4*>(
        &W[(size_t)(col0 + lr) * D_MODEL + k0 + lk]);
    const float4 wb = *reinterpret_cast<const float4*>(
        &W[(size_t)(col0 + lr) * D_MODEL + k0 + lk + 4]);
    __syncthreads();
    Xs[lk + 0][lr] = xa.x; Xs[lk + 1][lr] = xa.y;
    Xs[lk + 2][lr] = xa.z; Xs[lk + 3][lr] = xa.w;
    Xs[lk + 4][lr] = xb.x; Xs[lk + 5][lr] = xb.y;
    Xs[lk + 6][lr] = xb.z; Xs[lk + 7][lr] = xb.w;
    Ws[lk + 0][lr] = wa.x; Ws[lk + 1][lr] = wa.y;
    Ws[lk + 2][lr] = wa.z; Ws[lk + 3][lr] = wa.w;
    Ws[lk + 4][lr] = wb.x; Ws[lk + 5][lr] = wb.y;
    Ws[lk + 6][lr] = wb.z; Ws[lk + 7][lr] = wb.w;
    __syncthreads();
#pragma unroll
    for (int kk = 0; kk < 16; ++kk) {
      float a[8], bb[8];
      *reinterpret_cast<float4*>(&a[0]) =
          *reinterpret_cast<const float4*>(&Xs[kk][ty * 4]);
      *reinterpret_cast<float4*>(&a[4]) =
          *reinterpret_cast<const float4*>(&Xs[kk][64 + ty * 4]);
      *reinterpret_cast<float4*>(&bb[0]) =
          *reinterpret_cast<const float4*>(&Ws[kk][tx * 4]);
      *reinterpret_cast<float4*>(&bb[4]) =
          *reinterpret_cast<const float4*>(&Ws[kk][64 + tx * 4]);
#pragma unroll
      for (int i = 0; i < 8; ++i)
#pragma unroll
        for (int j = 0; j < 8; ++j) acc[i][j] += a[i] * bb[j];
    }
  }

  float bA[4], bB[4];
  *reinterpret_cast<float4*>(&bA[0]) =
      *reinterpret_cast<const float4*>(&bias[col0 + tx * 4]);
  *reinterpret_cast<float4*>(&bB[0]) =
      *reinterpret_cast<const float4*>(&bias[col0 + 64 + tx * 4]);

  if (blockIdx.z < 2) {
    unsigned short* hp = (blockIdx.z == 0) ? q_hi : k_hi;
    unsigned short* lp = (blockIdx.z == 0) ? q_lo : k_lo;
#pragma unroll
    for (int i = 0; i < 8; ++i) {
      const int row = row0 + ((i < 4) ? (ty * 4 + i) : (64 + ty * 4 + (i - 4)));
#pragma unroll
      for (int grp = 0; grp < 2; ++grp) {
        unsigned hw[2], lw[2];
        unsigned short hs[4], ls[4];
#pragma unroll
        for (int j = 0; j < 4; ++j) {
          const float y = acc[i][grp * 4 + j] + (grp ? bB[j] : bA[j]);
          const unsigned short hb = bf16_rne(y);
          hs[j] = hb;
          ls[j] = bf16_rne(y - bf16f(hb));
        }
        hw[0] = (unsigned)hs[0] | ((unsigned)hs[1] << 16);
        hw[1] = (unsigned)hs[2] | ((unsigned)hs[3] << 16);
        lw[0] = (unsigned)ls[0] | ((unsigned)ls[1] << 16);
        lw[1] = (unsigned)ls[2] | ((unsigned)ls[3] << 16);
        const size_t off = (size_t)row * D_MODEL + col0 + grp * 64 + tx * 4;
        *reinterpret_cast<uint2*>(&hp[off]) = make_uint2(hw[0], hw[1]);
        *reinterpret_cast<uint2*>(&lp[off]) = make_uint2(lw[0], lw[1]);
      }
    }
  } else {
#pragma unroll
    for (int i = 0; i < 8; ++i) {
      const int row = row0 + ((i < 4) ? (ty * 4 + i) : (64 + ty * 4 + (i - 4)));
#pragma unroll
      for (int grp = 0; grp < 2; ++grp) {
        unsigned short hs[4];
#pragma unroll
        for (int j = 0; j < 4; ++j)
          hs[j] = bf16_rne(acc[i][grp * 4 + j] + (grp ? bB[j] : bA[j]));
        const size_t off = (size_t)row * D_MODEL + col0 + grp * 64 + tx * 4;
        *reinterpret_cast<uint2*>(&v_b[off]) = make_uint2(
            (unsigned)hs[0] | ((unsigned)hs[1] << 16),
            (unsigned)hs[2] | ((unsigned)hs[3] << 16));
      }
    }
  }
}

// ---------------------------------------------------------------------------
// V transpose: v_b [b*2048+kpos][512] -> vt [b*512+col][2048] (bf16).
// 64x64 tiles through LDS. Tiny (16 MB traffic, ~5 us); conflicts tolerated.
// ---------------------------------------------------------------------------
__global__ __launch_bounds__(256) void vtrans_kernel(
    const unsigned short* __restrict__ vb, unsigned short* __restrict__ vt) {
  __shared__ unsigned short T[64][72];
  const int kt = blockIdx.x, ct = blockIdx.y, b = blockIdx.z;
  const int t = threadIdx.x;
  const int r = t >> 3, seg = t & 7;
#pragma unroll
  for (int i = 0; i < 2; ++i) {
    const int row = r + 32 * i;
    const uint4 val = *reinterpret_cast<const uint4*>(
        &vb[((size_t)(b * 2048 + kt * 64 + row)) * 512 + ct * 64 + seg * 8]);
    *reinterpret_cast<uint4*>(&T[row][seg * 8]) = val;
  }
  __syncthreads();
#pragma unroll
  for (int i = 0; i < 2; ++i) {
    const int col = r + 32 * i;  // output row = column of source tile
    unsigned short tmp[8];
#pragma unroll
    for (int j = 0; j < 8; ++j) tmp[j] = T[seg * 8 + j][col];
    *reinterpret_cast<uint4*>(
        &vt[((size_t)(b * 512 + ct * 64 + col)) * 2048 + kt * 64 + seg * 8]) =
        *reinterpret_cast<uint4*>(&tmp[0]);
  }
}

// ---------------------------------------------------------------------------
// Flash attention, bf16 MFMA (16x16x32), fp32-grade via hi/lo splits.
// 4 waves x 32 q-rows = 128 q-rows/block; BK=64. S = (Qhi+Qlo)(Khi+Klo)^T
// via 3-term MFMA (drop lo*lo); P split hi/lo through wave-private LDS
// (u32 = hi | lo<<16, no barrier needed); V single bf16 (Vt d-major).
// C/D layout (m89): col=lane&15, row=(lane>>4)*4+reg. A/B frags: 8
// k-contiguous bf16 per lane at k=8*(lane>>4)+j. All LDS access patterns
// analyzed for even bank load (pitch 72 elem / 68 u32).
// ---------------------------------------------------------------------------
__global__ __launch_bounds__(256, 2) void mha_attn_mfma(
    const unsigned short* __restrict__ qhi, const unsigned short* __restrict__ qlo,
    const unsigned short* __restrict__ khi, const unsigned short* __restrict__ klo,
    const unsigned short* __restrict__ vt, float* __restrict__ out) {
  __shared__ unsigned short Khs[64][72];
  __shared__ unsigned short Kls[64][72];
  __shared__ unsigned short Vts[64][72];
  __shared__ unsigned Pl[4][32][68];

  const int tid = threadIdx.x;
  const int w = tid >> 6;
  const int lane = tid & 63;
  const int g = lane >> 4;   // 0..3
  const int c = lane & 15;   // 0..15
  const int bid = blockIdx.x;
  const int qb = bid & 15;
  const int h = (bid >> 4) & 7;
  const int b = bid >> 7;
  const int q0 = qb * 128 + w * 32;

  // Q fragments (hi/lo), loaded once from global.
  v8s qfh[2][2], qfl[2][2];
#pragma unroll
  for (int qt = 0; qt < 2; ++qt)
#pragma unroll
    for (int kh = 0; kh < 2; ++kh) {
      const size_t off = ((size_t)(b * 2048 + q0 + qt * 16 + c)) * 512 +
                         h * 64 + kh * 32 + g * 8;
      qfh[qt][kh] = *reinterpret_cast<const v8s*>(&qhi[off]);
      qfl[qt][kh] = *reinterpret_cast<const v8s*>(&qlo[off]);
    }

  v4f ctx[2][4];
#pragma unroll
  for (int qt = 0; qt < 2; ++qt)
#pragma unroll
    for (int dt = 0; dt < 4; ++dt) ctx[qt][dt] = (v4f){0.f, 0.f, 0.f, 0.f};
  float mrun[2][4], lrun[2][4];
#pragma unroll
  for (int qt = 0; qt < 2; ++qt)
#pragma unroll
    for (int r = 0; r < 4; ++r) {
      mrun[qt][r] = -1.0e30f;
      lrun[qt][r] = 0.f;
    }

  const int srow = tid >> 3;  // 0..31
  const int sseg = tid & 7;   // 0..7

  for (int kt = 0; kt < SEQ / 64; ++kt) {
    // stage loads issued before the barrier (overlap prior compute)
    uint4 sk[2], sl[2], sv[2];
#pragma unroll
    for (int i = 0; i < 2; ++i) {
      const int r = srow + 32 * i;
      const size_t ka =
          ((size_t)(b * 2048 + kt * 64 + r)) * 512 + h * 64 + sseg * 8;
      sk[i] = *reinterpret_cast<const uint4*>(&khi[ka]);
      sl[i] = *reinterpret_cast<const uint4*>(&klo[ka]);
      const size_t va =
          ((size_t)(b * 512 + h * 64 + r)) * 2048 + kt * 64 + sseg * 8;
      sv[i] = *reinterpret_cast<const uint4*>(&vt[va]);
    }
    __syncthreads();
#pragma unroll
    for (int i = 0; i < 2; ++i) {
      const int r = srow + 32 * i;
      *reinterpret_cast<uint4*>(&Khs[r][sseg * 8]) = sk[i];
      *reinterpret_cast<uint4*>(&Kls[r][sseg * 8]) = sl[i];
      *reinterpret_cast<uint4*>(&Vts[r][sseg * 8]) = sv[i];
    }
    __syncthreads();

    // ---- QK^T: 3-term split, 48 MFMAs ----
    v4f s[2][4];
#pragma unroll
    for (int qt = 0; qt < 2; ++qt)
#pragma unroll
      for (int ct = 0; ct < 4; ++ct) s[qt][ct] = (v4f){0.f, 0.f, 0.f, 0.f};
#pragma unroll
    for (int kh = 0; kh < 2; ++kh)
#pragma unroll
      for (int ct = 0; ct < 4; ++ct) {
        const v8s bh =
            *reinterpret_cast<const v8s*>(&Khs[ct * 16 + c][kh * 32 + g * 8]);
        const v8s bl =
            *reinterpret_cast<const v8s*>(&Kls[ct * 16 + c][kh * 32 + g * 8]);
#pragma unroll
        for (int qt = 0; qt < 2; ++qt) {
          s[qt][ct] = MFMA16(qfh[qt][kh], bh, s[qt][ct]);
          s[qt][ct] = MFMA16(qfh[qt][kh], bl, s[qt][ct]);
          s[qt][ct] = MFMA16(qfl[qt][kh], bh, s[qt][ct]);
        }
      }

    // ---- scale + online softmax ----
#pragma unroll
    for (int qt = 0; qt < 2; ++qt)
#pragma unroll
      for (int ct = 0; ct < 4; ++ct) s[qt][ct] *= 0.125f;

    float al[2][4];
#pragma unroll
    for (int qt = 0; qt < 2; ++qt)
#pragma unroll
      for (int r = 0; r < 4; ++r) {
        float mx = fmaxf(fmaxf(s[qt][0][r], s[qt][1][r]),
                         fmaxf(s[qt][2][r], s[qt][3][r]));
        mx = fmaxf(mx, __shfl_xor(mx, 1, 16));
        mx = fmaxf(mx, __shfl_xor(mx, 2, 16));
        mx = fmaxf(mx, __shfl_xor(mx, 4, 16));
        mx = fmaxf(mx, __shfl_xor(mx, 8, 16));
        const float mn = fmaxf(mrun[qt][r], mx);
        al[qt][r] = __expf(mrun[qt][r] - mn);
        mrun[qt][r] = mn;
      }
#pragma unroll
    for (int qt = 0; qt < 2; ++qt)
#pragma unroll
      for (int ct = 0; ct < 4; ++ct)
#pragma unroll
        for (int r = 0; r < 4; ++r)
          s[qt][ct][r] = __expf(s[qt][ct][r] - mrun[qt][r]);
#pragma unroll
    for (int qt = 0; qt < 2; ++qt)
#pragma unroll
      for (int r = 0; r < 4; ++r) {
        float ps = s[qt][0][r] + s[qt][1][r] + s[qt][2][r] + s[qt][3][r];
        ps += __shfl_xor(ps, 1, 16);
        ps += __shfl_xor(ps, 2, 16);
        ps += __shfl_xor(ps, 4, 16);
        ps += __shfl_xor(ps, 8, 16);
        lrun[qt][r] = lrun[qt][r] * al[qt][r] + ps;
      }
#pragma unroll
    for (int qt = 0; qt < 2; ++qt)
#pragma unroll
      for (int dt = 0; dt < 4; ++dt)
#pragma unroll
        for (int r = 0; r < 4; ++r) ctx[qt][dt][r] *= al[qt][r];

    // ---- P -> wave-private LDS (u32 = hi | lo<<16, trunc split) ----
#pragma unroll
    for (int qt = 0; qt < 2; ++qt)
#pragma unroll
      for (int ct = 0; ct < 4; ++ct)
#pragma unroll
        for (int r = 0; r < 4; ++r) {
          const float p = s[qt][ct][r];
          const unsigned u = __float_as_uint(p);
          const unsigned hi = u >> 16;
          const float lof = p - __uint_as_float(u & 0xffff0000u);
          const unsigned lo = __float_as_uint(lof) >> 16;
          Pl[w][qt * 16 + g * 4 + r][ct * 16 + c] = hi | (lo << 16);
        }

    // ---- PV: P(hi,lo) x Vt, 32 MFMAs (same-wave LDS RAW, no barrier) ----
#pragma unroll
    for (int kh = 0; kh < 2; ++kh) {
      v8s pah[2], pal[2];
#pragma unroll
      for (int qt = 0; qt < 2; ++qt) {
        const uint4 a0 = *reinterpret_cast<const uint4*>(
            &Pl[w][qt * 16 + c][kh * 32 + g * 8]);
        const uint4 a1 = *reinterpret_cast<const uint4*>(
            &Pl[w][qt * 16 + c][kh * 32 + g * 8 + 4]);
        uint4 hh, ll;
        hh.x = (a0.x & 0xffffu) | (a0.y << 16);
        hh.y = (a0.z & 0xffffu) | (a0.w << 16);
        hh.z = (a1.x & 0xffffu) | (a1.y << 16);
        hh.w = (a1.z & 0xffffu) | (a1.w << 16);
        ll.x = (a0.x >> 16) | (a0.y & 0xffff0000u);
        ll.y = (a0.z >> 16) | (a0.w & 0xffff0000u);
        ll.z = (a1.x >> 16) | (a1.y & 0xffff0000u);
        ll.w = (a1.z >> 16) | (a1.w & 0xffff0000u);
        pah[qt] = __builtin_bit_cast(v8s, hh);
        pal[qt] = __builtin_bit_cast(v8s, ll);
      }
#pragma unroll
      for (int dt = 0; dt < 4; ++dt) {
        const v8s vb =
            *reinterpret_cast<const v8s*>(&Vts[dt * 16 + c][kh * 32 + g * 8]);
#pragma unroll
        for (int qt = 0; qt < 2; ++qt) {
          ctx[qt][dt] = MFMA16(pah[qt], vb, ctx[qt][dt]);
          ctx[qt][dt] = MFMA16(pal[qt], vb, ctx[qt][dt]);
        }
      }
    }
  }

  // ---- epilogue: normalize and store fp32 ----
  float inv[2][4];
#pragma unroll
  for (int qt = 0; qt < 2; ++qt)
#pragma unroll
    for (int r = 0; r < 4; ++r) inv[qt][r] = 1.0f / lrun[qt][r];
#pragma unroll
  for (int qt = 0; qt < 2; ++qt)
#pragma unroll
    for (int dt = 0; dt < 4; ++dt)
#pragma unroll
      for (int r = 0; r < 4; ++r)
        out[((size_t)(b * 2048 + q0 + qt * 16 + g * 4 + r)) * 512 + h * 64 +
            dt * 16 + c] = ctx[qt][dt][r] * inv[qt][r];
}

extern "C" void kernel_launch(void* const* d_in, const int* in_sizes, int n_in,
                              void* d_out, int out_size, void* d_ws,
                              size_t ws_size, hipStream_t stream) {
  const float* q = (const float*)d_in[0];
  const float* k = (const float*)d_in[1];
  const float* v = (const float*)d_in[2];
  const float* Wq_w = (const float*)d_in[3];
  const float* Wq_b = (const float*)d_in[4];
  const float* Wk_w = (const float*)d_in[5];
  const float* Wk_b = (const float*)d_in[6];
  const float* Wv_w = (const float*)d_in[7];
  const float* Wv_b = (const float*)d_in[8];
  float* out = (float*)d_out;

  unsigned short* q_hi = (unsigned short*)d_ws;
  unsigned short* q_lo = q_hi + PLANE;
  unsigned short* k_hi = q_lo + PLANE;
  unsigned short* k_lo = k_hi + PLANE;
  unsigned short* v_b = k_lo + PLANE;
  unsigned short* vt = v_b + PLANE;  // total 6 planes * 8 MiB = 48 MiB

  dim3 pgrid(ROWS / 128, D_MODEL / 128, 3);
  mha_proj_kernel<<<pgrid, 256, 0, stream>>>(q, k, v, Wq_w, Wq_b, Wk_w, Wk_b,
                                             Wv_w, Wv_b, q_hi, q_lo, k_hi,
                                             k_lo, v_b);

  dim3 tgrid(SEQ / 64, D_MODEL / 64, BATCH);
  vtrans_kernel<<<tgrid, 256, 0, stream>>>(v_b, vt);

  dim3 agrid(BATCH * NUM_HEADS * (SEQ / 128));
  mha_attn_mfma<<<agrid, 256, 0, stream>>>(q_hi, q_lo, k_hi, k_lo, vt, out);
}